// Round 6
// baseline (135.777 us; speedup 1.0000x reference)
//
#include <hip/hip_runtime.h>

// LoRA forward: out = (h @ B^T) @ A^T, h: (16384, 4096) f32, rank 16.
// R6: two-kernel split, K1 rebuilt.
//  K1: 512 blocks x 1024 thr (2 blocks/CU). Block = (64 rows) x (d-half 2048).
//      h staged via LDS dbuf (32-KB chunks, global_load_lds w=16, XOR-swizzled
//      source); B via WAVE-UNIFORM scalar loads (zero LDS/VMEM cost) -- wave w
//      owns d-subslice, lane l owns row l. hr partials per half -> d_ws.
//  K2: out = (hr0+hr1) @ A^T. A fragment in VGPRs, broadcast hr loads,
//      nontemporal float4 stores. Barrier-free.

constexpr int  D  = 4096;
constexpr int  RK = 16;
constexpr long M  = 16384;

typedef float f32x4 __attribute__((ext_vector_type(4)));

__device__ __forceinline__ void gload_lds16(const float* src, float* ldsdst) {
  __builtin_amdgcn_global_load_lds(
      (const __attribute__((address_space(1))) void*)src,
      (__attribute__((address_space(3))) void*)ldsdst, 16, 0, 0);
}

__device__ __forceinline__ float dot4(float4 a, float4 b) {
  return a.x * b.x + a.y * b.y + a.z * b.z + a.w * b.w;
}

// ---------------------------------------------------------------- K1 -------
constexpr int K1_CH  = 128;             // floats of d per chunk per row (512B)
constexpr int K1_NCH = 2048 / K1_CH;    // 16 chunks per d-half

__global__ __launch_bounds__(1024) void lora_k1(
    const float* __restrict__ h,
    const float* __restrict__ matB,     // (RK, D) row-major
    float* __restrict__ hrp) {          // (2, M, RK) partials
  __shared__ float sH[2][64][K1_CH];    // 64 KB dbuf (XOR-swizzled slots)
  float* const red = &sH[0][0][0];      // [16][RK][64] alias (64 KB), reused

  const int tid  = threadIdx.x;
  const int w    = __builtin_amdgcn_readfirstlane(tid >> 6);  // wave 0..15
  const int l    = tid & 63;
  const long row0 = (long)(blockIdx.x >> 1) * 64;
  const int  half = blockIdx.x & 1;
  const int  dbase = half * 2048;

  // Per chunk: 32 KB = 32 wave-loads of 1 KB; wave w issues 2 (rows 4w..4w+3).
  // Load i covers rows 2i,2i+1; lane l -> row 2i+(l>>5), 16-B slot l&31.
  // LDS[R][sd] <- h[R][sd ^ (R&7)]  (swizzle in SOURCE; dest linear).
  auto STAGE = [&](int b, int c) {
#pragma unroll
    for (int j = 0; j < 2; ++j) {
      const int i  = w * 2 + j;
      const int R  = 2 * i + (l >> 5);
      const int sd = l & 31;
      const float* src = h + (row0 + R) * (long)D + dbase + c * K1_CH +
                         ((sd ^ (R & 7)) * 4);
      gload_lds16(src, &sH[b][2 * i][0]);
    }
  };

  float acc[RK];
#pragma unroll
  for (int r = 0; r < RK; ++r) acc[r] = 0.f;

  STAGE(0, 0);
#pragma unroll 1
  for (int c = 0; c < K1_NCH; ++c) {
    if (c + 1 < K1_NCH) {
      STAGE((c + 1) & 1, c + 1);
      asm volatile("s_waitcnt vmcnt(2)" ::: "memory");  // chunk c landed
    } else {
      asm volatile("s_waitcnt vmcnt(0)" ::: "memory");
    }
    __builtin_amdgcn_s_barrier();
    __builtin_amdgcn_sched_barrier(0);

    // thread (w,l): row l, d-subslice w (8 floats = slots 2w,2w+1)
    const int buf = c & 1;
    float4 h4[2];
#pragma unroll
    for (int q = 0; q < 2; ++q)
      h4[q] = *reinterpret_cast<const float4*>(
          &sH[buf][l][(((2 * w + q) ^ (l & 7)) * 4)]);  // deswizzle

    const float* bbase = matB + dbase + c * K1_CH + w * 8;  // wave-uniform
#pragma unroll
    for (int r = 0; r < RK; ++r) {
      const float4 b0 =
          *reinterpret_cast<const float4*>(bbase + (long)r * D);
      const float4 b1 =
          *reinterpret_cast<const float4*>(bbase + (long)r * D + 4);
      acc[r] += dot4(h4[0], b0) + dot4(h4[1], b1);
    }
    asm volatile("" ::: "memory");
    __builtin_amdgcn_s_barrier();   // computes done before buf overwrite
    __builtin_amdgcn_sched_barrier(0);
  }

  // all staging drained (vmcnt 0) and all computes done (last barrier):
  // safe to alias red over sH.
#pragma unroll
  for (int r = 0; r < RK; ++r) red[(w * RK + r) * 64 + l] = acc[r];
  __syncthreads();
  {
    const int r = tid >> 6, row = tid & 63;   // 1024 = 16 ranks x 64 rows
    float s = 0.f;
#pragma unroll
    for (int w2 = 0; w2 < 16; ++w2) s += red[(w2 * RK + r) * 64 + row];
    hrp[((long)half * M + row0 + row) * RK + r] = s;
  }
}

// ---------------------------------------------------------------- K2 -------
__global__ __launch_bounds__(256) void lora_k2(
    const float* __restrict__ hrp,    // (2, M, RK)
    const float* __restrict__ matA,   // (D, RK) row-major
    float* __restrict__ out) {
  const int tid = threadIdx.x;
  const int cs  = blockIdx.x & 3;          // column slice (1024 cols)
  const long row0 = (long)(blockIdx.x >> 2) * 64;
  const int c0 = cs * 1024 + tid * 4;      // 4 contiguous cols per thread

  float4 a[4][4];  // A rows for my 4 cols: 64 VGPRs, reused 64x
#pragma unroll
  for (int j = 0; j < 4; ++j)
#pragma unroll
    for (int q = 0; q < 4; ++q)
      a[j][q] = *reinterpret_cast<const float4*>(
          matA + (long)(c0 + j) * RK + q * 4);

#pragma unroll 4
  for (int rr = 0; rr < 64; ++rr) {
    const float4* p0 =
        reinterpret_cast<const float4*>(hrp + (row0 + rr) * RK);
    const float4* p1 =
        reinterpret_cast<const float4*>(hrp + (M + row0 + rr) * RK);
    const float4 h0 = p0[0] + p1[0], h1 = p0[1] + p1[1],
                 h2 = p0[2] + p1[2], h3 = p0[3] + p1[3];
    f32x4 o;
    o.x = dot4(h0, a[0][0]) + dot4(h1, a[0][1]) + dot4(h2, a[0][2]) +
          dot4(h3, a[0][3]);
    o.y = dot4(h0, a[1][0]) + dot4(h1, a[1][1]) + dot4(h2, a[1][2]) +
          dot4(h3, a[1][3]);
    o.z = dot4(h0, a[2][0]) + dot4(h1, a[2][1]) + dot4(h2, a[2][2]) +
          dot4(h3, a[2][3]);
    o.w = dot4(h0, a[3][0]) + dot4(h1, a[3][1]) + dot4(h2, a[3][2]) +
          dot4(h3, a[3][3]);
    __builtin_nontemporal_store(
        o, reinterpret_cast<f32x4*>(out + (row0 + rr) * (long)D + c0));
  }
}

extern "C" void kernel_launch(void* const* d_in, const int* in_sizes, int n_in,
                              void* d_out, int out_size, void* d_ws,
                              size_t ws_size, hipStream_t stream) {
  const float* h    = (const float*)d_in[0];
  const float* matA = (const float*)d_in[1];
  const float* matB = (const float*)d_in[2];
  float* out        = (float*)d_out;
  float* hrp        = (float*)d_ws;   // 2 * M * RK * 4 = 2 MiB scratch

  hipLaunchKernelGGL(lora_k1, dim3((int)(M / 64) * 2), dim3(1024), 0, stream,
                     h, matB, hrp);
  hipLaunchKernelGGL(lora_k2, dim3((int)(M / 64) * 4), dim3(256), 0, stream,
                     hrp, matA, out);
}